// Round 3
// baseline (112.775 us; speedup 1.0000x reference)
//
#include <hip/hip_runtime.h>
#include <cmath>

// Problem geometry (fixed: im is (1, 4096, 4096, 3) f32 NHWC)
constexpr int H   = 4096;
constexpr int W   = 4096;
constexpr int C   = 3;
constexpr int WF  = W * C;       // 12288 floats per image row
constexpr int EPT = 8;           // floats per thread
constexpr int TW  = 256 * EPT;   // 2048 floats per block
constexpr int RPT = 16;          // output rows per block

// Anscombe transform of 4 elements; OOB fill -0.375 maps to exactly 0.
__device__ __forceinline__ float4 ans4(float4 v) {
    float4 a;
    a.x = 2.0f * __builtin_amdgcn_sqrtf(v.x + 0.375f);
    a.y = 2.0f * __builtin_amdgcn_sqrtf(v.y + 0.375f);
    a.z = 2.0f * __builtin_amdgcn_sqrtf(v.z + 0.375f);
    a.w = 2.0f * __builtin_amdgcn_sqrtf(v.w + 0.375f);
    return a;
}

// Fused Anscombe -> separable 3x3 Gaussian (zero pad) -> clip -> inverse
// Anscombe. Barrier-free: each thread owns 8 consecutive flat floats (NHWC:
// horizontal pixel neighbors are at +/-3 flat). Horizontal taps cross thread
// boundaries only by 3 floats -> 6 scalar shfls from adjacent lanes; wave-edge
// lanes (0,63) patch their halo from a predicated global float4 load.
// Vertical 3-tap = rolling register window; row loads prefetched 1 stage ahead.
__global__ __launch_bounds__(256, 6) void anscombe_gauss_kernel(
    const float* __restrict__ in, float* __restrict__ out,
    float wa, float wb, float c1, float c3)
{
    const int tid  = threadIdx.x;
    const int lane = tid & 63;
    const int gc   = blockIdx.x * TW + tid * EPT;
    const int h0   = blockIdx.y * RPT;

    const bool isL = (lane == 0), isR = (lane == 63);
    const long haloOff = isL ? (long)gc - 4 : (long)gc + EPT;
    const bool haloAny = (isL && gc > 0) || (isR && gc + EPT < WF);

    const float4 cfill = make_float4(-0.375f, -0.375f, -0.375f, -0.375f);

    auto loadrow = [&](int hrow, float4& lo, float4& hi, float4& ha) {
        lo = cfill; hi = cfill; ha = cfill;
        if ((unsigned)hrow < (unsigned)H) {
            const float* rp = in + (long)hrow * WF;
            lo = *(const float4*)(rp + gc);
            hi = *(const float4*)(rp + gc + 4);
            if (haloAny) ha = *(const float4*)(rp + haloOff);
        }
    };

    float4 nlo, nhi, nha;
    loadrow(h0 - 1, nlo, nhi, nha);

    float hp[8] = {0,0,0,0,0,0,0,0};
    float hc[8] = {0,0,0,0,0,0,0,0};

    #pragma unroll
    for (int s = 0; s < RPT + 2; ++s) {
        const float4 vlo = nlo, vhi = nhi, vha = nha;
        if (s < RPT + 1) loadrow(h0 + s, nlo, nhi, nha);  // prefetch next row

        const float4 alo = ans4(vlo), ahi = ans4(vhi), aha = ans4(vha);

        // in-wave neighbor exchange for the +/-3-float horizontal halo
        float em3 = __shfl_up(ahi.y, 1);    // element -3
        float em2 = __shfl_up(ahi.z, 1);    // element -2
        float em1 = __shfl_up(ahi.w, 1);    // element -1
        float ep8 = __shfl_down(alo.x, 1);  // element 8
        float ep9 = __shfl_down(alo.y, 1);  // element 9
        float epA = __shfl_down(alo.z, 1);  // element 10
        if (isL) { em3 = aha.y; em2 = aha.z; em1 = aha.w; }
        if (isR) { ep8 = aha.x; ep9 = aha.y; epA = aha.z; }

        const float e0 = alo.x, e1 = alo.y, e2 = alo.z, e3 = alo.w;
        const float e4 = ahi.x, e5 = ahi.y, e6 = ahi.z, e7 = ahi.w;

        float hn[8];
        hn[0] = wa * (em3 + e3) + wb * e0;
        hn[1] = wa * (em2 + e4) + wb * e1;
        hn[2] = wa * (em1 + e5) + wb * e2;
        hn[3] = wa * (e0  + e6) + wb * e3;
        hn[4] = wa * (e1  + e7) + wb * e4;
        hn[5] = wa * (e2  + ep8) + wb * e5;
        hn[6] = wa * (e3  + ep9) + wb * e6;
        hn[7] = wa * (e4  + epA) + wb * e7;

        if (s >= 2) {
            const int ho = h0 + s - 2;
            float o[8];
            #pragma unroll
            for (int j = 0; j < 8; ++j) {
                float y = wa * (hp[j] + hn[j]) + wb * hc[j];
                y = fminf(fmaxf(y, 0.0f), 255.0f);
                // y >= ~0.17 always (center tap always in-image): rcp safe
                float ry = __builtin_amdgcn_rcpf(y);
                o[j] = fmaf(0.25f * y, y,
                        fmaf(ry, fmaf(ry, fmaf(ry, c3, -1.375f), c1), -0.125f));
            }
            float* op = out + (long)ho * WF + gc;
            *(float4*)(op)     = make_float4(o[0], o[1], o[2], o[3]);
            *(float4*)(op + 4) = make_float4(o[4], o[5], o[6], o[7]);
        }
        #pragma unroll
        for (int j = 0; j < 8; ++j) { hp[j] = hc[j]; hc[j] = hn[j]; }
    }
}

extern "C" void kernel_launch(void* const* d_in, const int* in_sizes, int n_in,
                              void* d_out, int out_size, void* d_ws, size_t ws_size,
                              hipStream_t stream) {
    const float* in = (const float*)d_in[0];
    float* out      = (float*)d_out;

    // Separable Gaussian weights (double precision on host).
    // 2D normalized kernel == outer([a,b,a],[a,b,a]) with a+b+a == 1.
    const double sig2x2 = 2.0 * 1.3 * 1.3;
    const double e1     = std::exp(-1.0 / sig2x2);
    const double inv1d  = 1.0 / (1.0 + 2.0 * e1);
    const float  wa     = (float)(e1 * inv1d);
    const float  wb     = (float)inv1d;

    const double s  = std::sqrt(1.5);
    const float  c1 = (float)(0.25  * s);
    const float  c3 = (float)(0.625 * s);

    dim3 grid(WF / TW, H / RPT);   // 6 x 256
    anscombe_gauss_kernel<<<grid, 256, 0, stream>>>(in, out, wa, wb, c1, c3);
}

// Round 5
// 84.527 us; speedup vs baseline: 1.3342x; 1.3342x over previous
//
#include <hip/hip_runtime.h>
#include <cmath>

// Problem geometry (fixed: im is (1, 4096, 4096, 3) f32 NHWC)
constexpr int H   = 4096;
constexpr int W   = 4096;
constexpr int C   = 3;
constexpr int WF  = W * C;       // 12288 floats per image row
constexpr int EPT = 8;           // floats per thread
constexpr int TW  = 256 * EPT;   // 2048 floats per block
constexpr int RPT = 16;          // output rows per block

typedef float f32x4 __attribute__((ext_vector_type(4)));  // clang vector (nt-store ok)

__device__ __forceinline__ float ans1(float v) {
    return 2.0f * __builtin_amdgcn_sqrtf(v + 0.375f);
}
__device__ __forceinline__ float4 ans4(float4 v) {
    return make_float4(ans1(v.x), ans1(v.y), ans1(v.z), ans1(v.w));
}

// Fused Anscombe -> separable 3x3 Gaussian (zero pad) -> clip -> inverse
// Anscombe. Fully thread-independent: each thread owns 8 consecutive flat
// floats and loads its +-4-float halo directly (aligned float4s that are the
// neighbor threads' core chunks -> L1 hits, no HBM amplification). No LDS,
// no barriers, no cross-lane ops, no divergent loads (halo OOB = address
// clamp + cndmask fill; only 2 lanes in the whole grid). Vertical 3-tap is a
// rolling register window; next row's 4 loads are prefetched before compute.
__global__ __launch_bounds__(256, 4) void anscombe_gauss_kernel(
    const float* __restrict__ in, float* __restrict__ out,
    float wa, float wb, float c1, float c3)
{
    const int tid = threadIdx.x;
    const int gc  = blockIdx.x * TW + tid * EPT;
    const int h0  = blockIdx.y * RPT;

    const bool okL = (gc >= 4);          // left-halo float4 fully in-row
    const bool okR = (gc + 12 <= WF);    // right-halo float4 fully in-row
    const int offL = okL ? gc - 4 : gc;  // clamped (safe) addresses
    const int offR = okR ? gc + 8 : gc;

    const float4 cfill = make_float4(-0.375f, -0.375f, -0.375f, -0.375f);

    auto loadrow = [&](int h, float4& lo, float4& hi, float4& hl, float4& hr) {
        if ((unsigned)h < (unsigned)H) {
            const float* rp = in + (long)h * WF;
            lo = *(const float4*)(rp + gc);
            hi = *(const float4*)(rp + gc + 4);
            hl = *(const float4*)(rp + offL);
            hr = *(const float4*)(rp + offR);
            if (!okL) hl = cfill;        // 1 lane in grid (branch-free select)
            if (!okR) hr = cfill;        // 1 lane in grid
        } else {
            lo = hi = hl = hr = cfill;   // zero row in AT domain
        }
    };

    float4 pl, ph, pL, pR;
    loadrow(h0 - 1, pl, ph, pL, pR);

    float hp[8] = {0,0,0,0,0,0,0,0};
    float hc[8] = {0,0,0,0,0,0,0,0};

    #pragma unroll
    for (int s = 0; s < RPT + 2; ++s) {
        const float4 vlo = pl, vhi = ph, vhl = pL, vhr = pR;
        if (s < RPT + 1) loadrow(h0 + s, pl, ph, pL, pR);   // prefetch next row

        const float4 alo = ans4(vlo), ahi = ans4(vhi);
        const float m3 = ans1(vhl.y), m2 = ans1(vhl.z), m1 = ans1(vhl.w);
        const float p8 = ans1(vhr.x), p9 = ans1(vhr.y), pA = ans1(vhr.z);

        const float e0 = alo.x, e1 = alo.y, e2 = alo.z, e3 = alo.w;
        const float e4 = ahi.x, e5 = ahi.y, e6 = ahi.z, e7 = ahi.w;

        float hn[8];
        hn[0] = wa * (m3 + e3) + wb * e0;
        hn[1] = wa * (m2 + e4) + wb * e1;
        hn[2] = wa * (m1 + e5) + wb * e2;
        hn[3] = wa * (e0 + e6) + wb * e3;
        hn[4] = wa * (e1 + e7) + wb * e4;
        hn[5] = wa * (e2 + p8) + wb * e5;
        hn[6] = wa * (e3 + p9) + wb * e6;
        hn[7] = wa * (e4 + pA) + wb * e7;

        if (s >= 2) {
            const int ho = h0 + s - 2;
            float o[8];
            #pragma unroll
            for (int j = 0; j < 8; ++j) {
                float y = wa * (hp[j] + hn[j]) + wb * hc[j];
                y = fminf(fmaxf(y, 0.0f), 255.0f);
                // y >= ~0.17 always (center tap always in-image): rcp safe
                float ry = __builtin_amdgcn_rcpf(y);
                o[j] = fmaf(0.25f * y, y,
                        fmaf(ry, fmaf(ry, fmaf(ry, c3, -1.375f), c1), -0.125f));
            }
            float* op = out + (long)ho * WF + gc;
            f32x4 o0 = {o[0], o[1], o[2], o[3]};
            f32x4 o1 = {o[4], o[5], o[6], o[7]};
            __builtin_nontemporal_store(o0, (f32x4*)op);
            __builtin_nontemporal_store(o1, (f32x4*)(op + 4));
        }
        #pragma unroll
        for (int j = 0; j < 8; ++j) { hp[j] = hc[j]; hc[j] = hn[j]; }
    }
}

extern "C" void kernel_launch(void* const* d_in, const int* in_sizes, int n_in,
                              void* d_out, int out_size, void* d_ws, size_t ws_size,
                              hipStream_t stream) {
    const float* in = (const float*)d_in[0];
    float* out      = (float*)d_out;

    // Separable Gaussian weights (double precision on host).
    // 2D normalized kernel == outer([a,b,a],[a,b,a]) with a+b+a == 1.
    const double sig2x2 = 2.0 * 1.3 * 1.3;
    const double e1     = std::exp(-1.0 / sig2x2);
    const double inv1d  = 1.0 / (1.0 + 2.0 * e1);
    const float  wa     = (float)(e1 * inv1d);
    const float  wb     = (float)inv1d;

    const double s  = std::sqrt(1.5);
    const float  c1 = (float)(0.25  * s);
    const float  c3 = (float)(0.625 * s);

    dim3 grid(WF / TW, H / RPT);   // 6 x 256
    anscombe_gauss_kernel<<<grid, 256, 0, stream>>>(in, out, wa, wb, c1, c3);
}